// Round 15
// baseline (79.651 us; speedup 1.0000x reference)
//
#include <hip/hip_runtime.h>
#include <hip/hip_bf16.h>
#include <cstdint>

// EdgeMLP R15 = R14 math (validated, absmax 1.17e-2) restructured for the
// 32-wave VGPR bucket: <=64 VGPR via depth-2 pipeline + transient-minimal
// epilogue + scales in global (L1) + w2/b1 from LDS. LDS 20.5KB -> 7 blocks/CU,
// launch_bounds(256,8) -> 28 waves/CU (1.75x R14 residency).
// ws: [hq: nNodes*64 i8][scf: nG64 f32 folded][swbits u32][w1q 16K i8][w2tab 2048 bf16]

constexpr int EMB = 64;
constexpr int HID = 128;

typedef int   i32x4 __attribute__((ext_vector_type(4)));
typedef short s16x8 __attribute__((ext_vector_type(8)));
typedef float f32x4 __attribute__((ext_vector_type(4)));

__device__ __forceinline__ unsigned short f2bf(float x) {
    unsigned u = __float_as_uint(x);
    u = (u + 0x7fffu + ((u >> 16) & 1u)) >> 16;   // RNE
    return (unsigned short)u;
}

// ---- prep A: global max|W1| via per-wave atomicMax on float bits ----
__global__ void w1max_kernel(const float* __restrict__ W1, unsigned* __restrict__ swbits) {
    const int i = blockIdx.x * 256 + threadIdx.x;   // grid 16 -> 4096 thr x 4 elems
    float4 v = *reinterpret_cast<const float4*>(W1 + (size_t)i * 4);
    float m = fmaxf(fmaxf(fabsf(v.x), fabsf(v.y)), fmaxf(fabsf(v.z), fabsf(v.w)));
    #pragma unroll
    for (int off = 1; off < 64; off <<= 1) m = fmaxf(m, __shfl_xor(m, off, 64));
    if ((threadIdx.x & 63) == 0) atomicMax(swbits, __float_as_uint(m));
}

// ---- prep B: fused per-64-node-group max + quantize; writes PRE-FOLDED scale ----
__global__ void quant_h_fused(const float* __restrict__ h, const unsigned* __restrict__ swb,
                              float* __restrict__ scf, char* __restrict__ hq, int total) {
    __shared__ float red[4];
    const int g = blockIdx.x, t = threadIdx.x;
    const size_t base = (size_t)g * 4096 + (size_t)t * 16;
    const bool full = (base < (size_t)total);
    float4 v[4];
    float m = 0.f;
    if (full) {
        #pragma unroll
        for (int q = 0; q < 4; ++q) {
            v[q] = *reinterpret_cast<const float4*>(h + base + q * 4);
            m = fmaxf(m, fmaxf(fmaxf(fabsf(v[q].x), fabsf(v[q].y)),
                               fmaxf(fabsf(v[q].z), fabsf(v[q].w))));
        }
    }
    #pragma unroll
    for (int off = 1; off < 64; off <<= 1) m = fmaxf(m, __shfl_xor(m, off, 64));
    if ((t & 63) == 0) red[t >> 6] = m;
    __syncthreads();
    const float gmax = fmaxf(fmaxf(red[0], red[1]), fmaxf(red[2], red[3]));
    const float scale = fmaxf(gmax / 127.f, 1e-20f);
    if (t == 0) {
        const float swv = __uint_as_float(swb[0]) / 127.f;   // sw = max|W1|/127
        scf[g] = scale * swv;                                // pre-folded for main
    }
    if (!full) return;
    const float inv = 1.0f / scale;
    unsigned w[4];
    #pragma unroll
    for (int q = 0; q < 4; ++q) {
        int a = max(-127, min(127, __float2int_rn(v[q].x * inv)));
        int b = max(-127, min(127, __float2int_rn(v[q].y * inv)));
        int c = max(-127, min(127, __float2int_rn(v[q].z * inv)));
        int d = max(-127, min(127, __float2int_rn(v[q].w * inv)));
        w[q] = (a & 255) | ((b & 255) << 8) | ((c & 255) << 16) | ((unsigned)(d & 255) << 24);
    }
    *reinterpret_cast<uint4*>(hq + base) = make_uint4(w[0], w[1], w[2], w[3]);
}

// ---- prep C: W1 i8 fragments + W2 bf16 fragments (validated layouts) ----
__global__ void pack_tabs_i8(const float* __restrict__ W1, const float* __restrict__ W2,
                             const unsigned* __restrict__ swb,
                             char* __restrict__ w1q, unsigned short* __restrict__ w2t) {
    const int i = blockIdx.x * blockDim.x + threadIdx.x;
    if (i < 16384) {
        const int j = i & 15, lane = (i >> 4) & 63, half = (i >> 10) & 1, mt = i >> 11;
        const int k = half * 64 + (lane >> 4) * 16 + j;
        const int n = mt * 16 + (lane & 15);
        const float inv = 127.f / fmaxf(__uint_as_float(swb[0]), 1e-18f);
        w1q[i] = (char)max(-127, min(127, __float2int_rn(W1[(size_t)k * HID + n] * inv)));
    } else if (i < 16384 + 2048) {
        const int q = i - 16384;
        const int j = q & 7, lane = (q >> 3) & 63, ks = q >> 9;
        const int tc = lane & 15, bq = lane >> 4;
        const int mt = ks * 2 + (j >> 2), r = j & 3;
        w2t[q] = (tc < 2) ? f2bf(W2[(mt * 16 + bq * 4 + r) * 2 + tc]) : (unsigned short)0;
    }
}

// ---- main ----
__global__ __launch_bounds__(256, 8)   // force <=64 VGPR -> 32-wave bucket
void edge_mlp_i8v3(const char* __restrict__ hq,
                   const float* __restrict__ scf,
                   const char* __restrict__ w1q,
                   const unsigned short* __restrict__ w2t,
                   const int* __restrict__ eidx,
                   const float* __restrict__ b1,
                   const float* __restrict__ b2,
                   float* __restrict__ out, int E, int nTiles)
{
    __shared__ uint4 w1s[1024];   // 16 KB i8 W1 fragments
    __shared__ uint4 w2s[256];    // 4 KB  W2 bf16 fragments
    __shared__ float b1s[128];    // 512 B
    {
        const uint4* src = reinterpret_cast<const uint4*>(w1q);
        #pragma unroll
        for (int r = 0; r < 4; ++r)
            w1s[r * 256 + threadIdx.x] = src[r * 256 + threadIdx.x];
        w2s[threadIdx.x] = *(reinterpret_cast<const uint4*>(w2t) + threadIdx.x);
        if (threadIdx.x < 128) b1s[threadIdx.x] = b1[threadIdx.x];
    }
    __syncthreads();

    const int t = threadIdx.x, wid = t >> 6, lane = t & 63;
    const int tc = lane & 15, bq = lane >> 4;
    const i32x4* wq  = reinterpret_cast<const i32x4*>(w1s) + lane;  // + (mt*2+half)*64
    const s16x8* wf2 = reinterpret_cast<const s16x8*>(w2s) + lane;  // + ks2*64
    const float* b1v = b1s + bq * 4;                                // + mt*16

    const float a20 = (bq == 0) ? b2[0] : 0.f;
    const float a21 = (bq == 0) ? b2[1] : 0.f;

    const int stride = gridDim.x * 4;
    int tile = blockIdx.x * 4 + wid;
    if (tile >= nTiles) return;

    auto LOADIDX = [&](int tl, int& s, int& d) {
        if (tl < nTiles) {
            const int e = min(tl * 16 + tc, E - 1);
            s = eidx[e]; d = eidx[E + e];
        } else { s = 0; d = 0; }
    };
    auto GATHER = [&](int s, int d, i32x4& xS, i32x4& xD, float& ssw, float& sdw) {
        xS = *reinterpret_cast<const i32x4*>(hq + (size_t)s * EMB + bq * 16);
        xD = *reinterpret_cast<const i32x4*>(hq + (size_t)d * EMB + bq * 16);
        ssw = scf[s >> 6];
        sdw = scf[d >> 6];
    };
    auto COMPUTE = [&](int tl, i32x4 xS, i32x4 xD, float ssw, float sdw) {
        const i32x4 z = {0, 0, 0, 0};
        f32x4 o = {a20, a21, 0.f, 0.f};
        #pragma unroll
        for (int ks2 = 0; ks2 < 4; ++ks2) {
            s16x8 p;
            #pragma unroll
            for (int half = 0; half < 2; ++half) {
                const int mt = ks2 * 2 + half;
                i32x4 aS = __builtin_amdgcn_mfma_i32_16x16x64_i8(wq[(mt * 2 + 0) * 64], xS, z, 0, 0, 0);
                i32x4 aD = __builtin_amdgcn_mfma_i32_16x16x64_i8(wq[(mt * 2 + 1) * 64], xD, z, 0, 0, 0);
                const f32x4 bb = *reinterpret_cast<const f32x4*>(b1v + mt * 16);
                #pragma unroll
                for (int pr = 0; pr < 2; ++pr) {
                    const int r = pr * 2;
                    float h0 = fmaxf(fmaf((float)aS[r],     ssw, fmaf((float)aD[r],     sdw, bb[r]    )), 0.f);
                    float h1 = fmaxf(fmaf((float)aS[r + 1], ssw, fmaf((float)aD[r + 1], sdw, bb[r + 1])), 0.f);
                    __hip_bfloat162 bpk = __float22bfloat162_rn(make_float2(h0, h1));
                    reinterpret_cast<unsigned*>(&p)[half * 2 + pr] = *reinterpret_cast<unsigned*>(&bpk);
                }
            }
            o = __builtin_amdgcn_mfma_f32_16x16x32_bf16(wf2[ks2 * 64], p, o, 0, 0, 0);
        }
        if (lane < 16) {
            const int eo = tl * 16 + lane;
            if (eo < E)
                *reinterpret_cast<float2*>(out + (size_t)eo * 2) = make_float2(o[0], o[1]);
        }
    };

    // ---- depth-2 pipeline (R9-validated skeleton) ----
    int s0, d0, s1, d1;
    i32x4 xS0, xD0, xS1, xD1;
    float a0s, a0d, a1s, a1d;

    LOADIDX(tile, s0, d0);
    GATHER(s0, d0, xS0, xD0, a0s, a0d);
    LOADIDX(tile + stride, s1, d1);

    while (true) {
        GATHER(s1, d1, xS1, xD1, a1s, a1d);
        LOADIDX(tile + 2 * stride, s0, d0);
        COMPUTE(tile, xS0, xD0, a0s, a0d);
        tile += stride;
        if (tile >= nTiles) break;

        GATHER(s0, d0, xS0, xD0, a0s, a0d);
        LOADIDX(tile + 2 * stride, s1, d1);
        COMPUTE(tile, xS1, xD1, a1s, a1d);
        tile += stride;
        if (tile >= nTiles) break;
    }
}

// ---- fallback (ws too small; correct but slow) ----
__global__ void edge_mlp_naive(const float* __restrict__ h, const int* __restrict__ eidx,
                               const float* __restrict__ W1, const float* __restrict__ b1,
                               const float* __restrict__ W2, const float* __restrict__ b2,
                               float* __restrict__ out, int E) {
    const int e = blockIdx.x * 256 + threadIdx.x;
    if (e >= E) return;
    const float* hs = h + (size_t)eidx[e] * EMB;
    const float* hd = h + (size_t)eidx[E + e] * EMB;
    float o0 = b2[0], o1 = b2[1];
    for (int j = 0; j < HID; ++j) {
        float a = b1[j];
        for (int k = 0; k < EMB; ++k)
            a += hs[k] * W1[(size_t)k * HID + j] + hd[k] * W1[(size_t)(k + EMB) * HID + j];
        a = fmaxf(a, 0.f);
        o0 = fmaf(a, W2[j * 2 + 0], o0);
        o1 = fmaf(a, W2[j * 2 + 1], o1);
    }
    out[(size_t)e * 2 + 0] = o0;
    out[(size_t)e * 2 + 1] = o1;
}

extern "C" void kernel_launch(void* const* d_in, const int* in_sizes, int n_in,
                              void* d_out, int out_size, void* d_ws, size_t ws_size,
                              hipStream_t stream)
{
    const float* h  = (const float*)d_in[0];
    const int*   ei = (const int*)d_in[1];
    const float* W1 = (const float*)d_in[2];
    const float* b1 = (const float*)d_in[3];
    const float* W2 = (const float*)d_in[4];
    const float* b2 = (const float*)d_in[5];
    float* out = (float*)d_out;

    const int nNodes = in_sizes[0] / EMB;
    const int E      = in_sizes[1] / 2;
    const int nTiles = (E + 15) / 16;
    const int nG64   = (nNodes + 63) >> 6;
    const int total  = nNodes * EMB;

    const size_t hq_off = 0;
    const size_t sc_off = (size_t)nNodes * EMB;
    const size_t sw_off = sc_off + (size_t)nG64 * 4;
    const size_t w1_off = (sw_off + 4 + 15) & ~(size_t)15;
    const size_t w2_off = w1_off + 16384;
    const size_t need   = w2_off + 2048 * 2;

    if (ws_size >= need) {
        char*  ws  = (char*)d_ws;
        char*  hq  = ws + hq_off;
        float* scf = (float*)(ws + sc_off);
        unsigned* swb = (unsigned*)(ws + sw_off);
        char*  w1q = ws + w1_off;
        unsigned short* w2t = (unsigned short*)(ws + w2_off);

        hipMemsetAsync(swb, 0, 4, stream);
        hipLaunchKernelGGL(w1max_kernel, dim3(16), dim3(256), 0, stream, W1, swb);
        hipLaunchKernelGGL(quant_h_fused, dim3(nG64), dim3(256), 0, stream,
                           h, swb, scf, hq, total);
        hipLaunchKernelGGL(pack_tabs_i8, dim3(72), dim3(256), 0, stream,
                           W1, W2, swb, w1q, w2t);
        hipLaunchKernelGGL(edge_mlp_i8v3, dim3(1792), dim3(256), 0, stream,
                           hq, scf, w1q, w2t, ei, b1, b2, out, E, nTiles);
    } else {
        hipLaunchKernelGGL(edge_mlp_naive, dim3((E + 255) / 256), dim3(256), 0, stream,
                           h, ei, W1, b1, W2, b2, out, E);
    }
}